// Round 9
// baseline (1100.942 us; speedup 1.0000x reference)
//
#include <hip/hip_runtime.h>

#define D_ 1024
#define T_ 1024
#define B_ 16

typedef short s16x8 __attribute__((ext_vector_type(8)));
typedef float f32x4 __attribute__((ext_vector_type(4)));

__device__ __forceinline__ unsigned short bf16_rne(float f){
  unsigned int u = __builtin_bit_cast(unsigned int, f);
  u += 0x7FFFu + ((u >> 16) & 1u);
  return (unsigned short)(u >> 16);
}
__device__ __forceinline__ float bf16_tof(unsigned short h){
  unsigned int u = ((unsigned int)h) << 16;
  return __builtin_bit_cast(float, u);
}
__device__ __forceinline__ float fsig(float x){ return 1.0f/(1.0f+__expf(-x)); }
__device__ __forceinline__ float ftanh(float x){ return 2.0f*fsig(2.0f*x)-1.0f; }

// MFMA wrapper robust to builtin operand type (short8 vs __bf16 x8)
template <typename V>
__device__ __forceinline__ auto mfma_try(V a, V b, f32x4 c, int)
    -> decltype(__builtin_amdgcn_mfma_f32_16x16x32_bf16(a, b, c, 0, 0, 0)) {
  return __builtin_amdgcn_mfma_f32_16x16x32_bf16(a, b, c, 0, 0, 0);
}
template <typename V>
__device__ __forceinline__ f32x4 mfma_try(V a, V b, f32x4 c, long) {
  typedef __bf16 bf16x8 __attribute__((ext_vector_type(8)));
  return __builtin_amdgcn_mfma_f32_16x16x32_bf16(
      __builtin_bit_cast(bf16x8, a), __builtin_bit_cast(bf16x8, b), c, 0, 0, 0);
}
__device__ __forceinline__ f32x4 MFMA(s16x8 a, s16x8 b, f32x4 c){
  return mfma_try(a, b, c, 0);
}

// ================= device task bodies =================

__device__ __forceinline__ void dev_conv4(const float* __restrict__ s,
                                          unsigned short* __restrict__ d, int g){
  float4 v = *(const float4*)(s + (size_t)g*4);
  ushort4 o; o.x=bf16_rne(v.x); o.y=bf16_rne(v.y); o.z=bf16_rne(v.z); o.w=bf16_rne(v.w);
  *(ushort4*)(d + (size_t)g*4) = o;
}

// pack f32 row-major weight [rowOff+K, Nsrc] into MFMA B-fragment order (bf16)
// slot = ((nt*KT + kt)*64 + lane) holds B[kt*32+(lane>>4)*8+j][nt*16+(lane&15)]
__device__ __forceinline__ void dev_fragprep(const float* __restrict__ w, int rowOff,
                                             int KT, int Nsrc,
                                             unsigned short* __restrict__ dst, int slot){
  int lane = slot & 63; int tmp = slot >> 6; int kt = tmp % KT; int nt = tmp / KT;
  int kbase = kt*32 + (lane>>4)*8; int col = nt*16 + (lane&15);
  unsigned short* o = dst + (size_t)slot*8;
  #pragma unroll
  for (int j=0;j<8;j++) o[j] = bf16_rne(w[(size_t)(rowOff + kbase + j)*Nsrc + col]);
}

// window means at the 64 do2 points
__device__ __forceinline__ void dev_bm(const float* __restrict__ x,
                                       unsigned short* __restrict__ bm, int blk, int tid){
  int e = blk >> 4; int b = blk & 15;
  int tc = 16*(e+1); int hi = tc-2; int lo = tc-33; if (lo < 0) lo = 0;
  const float* xb = x + (size_t)b*T_*D_;
  for (int d = tid; d < D_; d += 256){
    float s = 0.f;
    for (int ss = lo; ss <= hi; ++ss) s += xb[(size_t)ss*D_ + d];
    bm[((size_t)(e*16+b))*D_ + d] = bf16_rne(s * (1.0f/32.0f));
  }
}

__device__ __forceinline__ void dev_bconst(const float* __restrict__ wf, const float* __restrict__ bf,
                                           const float* __restrict__ b1, const float* __restrict__ b2,
                                           const float* __restrict__ b3, float* __restrict__ bc,
                                           int blk, int tid){
  __shared__ float part[4][64];
  int n = blk*64 + (tid&63);
  int sl = tid>>6;
  float s = 0.f;
  for (int k=sl*256; k<(sl+1)*256; ++k){
    s += b1[k]*wf[(size_t)k*1024+n] + b2[k]*wf[(size_t)(1024+k)*1024+n] + b3[k]*wf[(size_t)(2048+k)*1024+n];
  }
  part[sl][tid&63] = s; __syncthreads();
  if (sl==0) bc[n] = bf[n] + part[0][tid] + part[1][tid] + part[2][tid] + part[3][tid];
}

__device__ __forceinline__ void dev_b2(const float* __restrict__ b_t2r, const float* __restrict__ w3o,
                                       const float* __restrict__ b3o, const float* __restrict__ w3n,
                                       const float* __restrict__ b3n, float* __restrict__ b2o,
                                       float* __restrict__ b2n, int tid){
  __shared__ float part[2][128];
  int idx = tid & 127; int sl = tid >> 7;
  int mat = idx>>6, n = idx&63;
  const float* w = mat ? w3n : w3o;
  float s = 0.f;
  for (int k=sl*512; k<(sl+1)*512; ++k) s += b_t2r[k]*w[(size_t)k*64+n];
  part[sl][idx] = s; __syncthreads();
  if (sl==0){
    float r = part[0][idx] + part[1][idx] + (mat? b3n[n] : b3o[n]);
    if (mat) b2n[n] = r; else b2o[n] = r;
  }
}

// generic bf16 MFMA GEMM tile: block covers rows [rb*rows, +rows) x cols [cb*64, +64)
// rows = 16 * (#waves in group)
__device__ __forceinline__ void dev_gemm(int M, int K,
    const unsigned short* __restrict__ A, int lda,
    const unsigned short* __restrict__ Bf,
    const float* __restrict__ bias, int act,
    float* __restrict__ C, int ldc, int cb, int rb, int tid, int rows){
  int KT = K >> 5;
  int w = tid >> 6, l = tid & 63;
  int rbase = rb*rows + w*16;
  int arow = rbase + (l & 15); if (arow >= M) arow = M-1;
  const unsigned short* Aptr = A + (size_t)arow*lda + ((l>>4)*8);
  const s16x8* B0 = (const s16x8*)Bf + ((size_t)(cb*4+0)*KT)*64 + l;
  const s16x8* B1 = (const s16x8*)Bf + ((size_t)(cb*4+1)*KT)*64 + l;
  const s16x8* B2 = (const s16x8*)Bf + ((size_t)(cb*4+2)*KT)*64 + l;
  const s16x8* B3 = (const s16x8*)Bf + ((size_t)(cb*4+3)*KT)*64 + l;
  f32x4 z = {0.f,0.f,0.f,0.f};
  f32x4 acc0=z, acc1=z, acc2=z, acc3=z;
  for (int kt=0; kt<KT; ++kt){
    s16x8 a = *(const s16x8*)(Aptr + (size_t)kt*32);
    acc0 = MFMA(a, B0[(size_t)kt*64], acc0);
    acc1 = MFMA(a, B1[(size_t)kt*64], acc1);
    acc2 = MFMA(a, B2[(size_t)kt*64], acc2);
    acc3 = MFMA(a, B3[(size_t)kt*64], acc3);
  }
  int r0 = (l>>4)*4;
  #pragma unroll
  for (int i=0;i<4;i++){
    f32x4 acc = i==0?acc0 : i==1?acc1 : i==2?acc2 : acc3;
    int col = (cb*4+i)*16 + (l&15);
    float bs = bias ? bias[col] : 0.0f;
    #pragma unroll
    for (int j=0;j<4;j++){
      int row = rbase + r0 + j;
      if (row < M){
        float vv = acc[j] + bs;
        if (act==1) vv = ftanh(vv);
        C[(size_t)row*ldc + col] = vv;
      }
    }
  }
}

// tier2/tier3 trajectory (sequential, tiny) — 1024 threads.
// bias32 hoisted per 8-event group (tier3 frozen within group).
__device__ void dev_traj(
    const float* __restrict__ v, const float* __restrict__ beta,
    const float* __restrict__ w_b32, const float* __restrict__ b_b32,
    const float* __restrict__ w2o, const float* __restrict__ b2o,
    const float* __restrict__ w2n, const float* __restrict__ b2n,
    unsigned short* __restrict__ t2traj, unsigned short* __restrict__ t3traj, int tid){
  __shared__ float t2[16*128];
  __shared__ float t3[16*64];
  __shared__ float var3[16*64];
  __shared__ float zb[16*64];
  __shared__ float rb[16*64];
  __shared__ float b32[16*128];
  for (int i=tid;i<2048;i+=1024){ t2[i]=0.f; t2traj[i]=0; }
  for (int i=tid;i<1024;i+=1024){
    int b=i>>6, n=i&63;
    t3[i]=0.f; var3[i]=1.f;
    t3traj[(size_t)b*128 + n] = 0;
    t3traj[(size_t)b*128 + 64 + n] = bf16_rne(1.f);
  }
  __syncthreads();
  for (int g=0; g<8; ++g){
    for (int i=tid;i<2048;i+=1024){
      int b=i>>7, n=i&127;
      float s=b_b32[n];
      for (int j=0;j<64;j++) s += t3[b*64+j]*w_b32[j*128+n];
      b32[i] = ftanh(s);
    }
    __syncthreads();
    for (int kk=0; kk<8; ++kk){
      int k = g*8 + kk + 1;
      for (int i=tid;i<2048;i+=1024){
        int b=i>>7, n=i&127;
        float t2b = t2[i] + b32[i];
        float bt = beta[(k-1)*16+b];
        float nv = t2b + bt*(v[(size_t)((k-1)*16+b)*128+n] - t2b);
        t2[i]=nv;
        t2traj[((size_t)k*16+b)*128+n] = bf16_rne(nv);
      }
    }
    __syncthreads();
    for (int i=tid;i<2048;i+=1024){
      int mat=i>>10, b=(i>>6)&15, n=i&63;
      const float* w = mat? w2n : w2o;
      float s = mat? b2n[n] : b2o[n];
      for (int j=0;j<128;j++) s += t2[b*128+j]*w[j*64+n];
      if (mat){ float r = (s>20.f)? s : log1pf(__expf(s)); rb[b*64+n]=r+0.01f; }
      else zb[b*64+n]=s;
    }
    __syncthreads();
    for (int i=tid;i<1024;i+=1024){
      int b=i>>6, n=i&63;
      float sp = 0.99f*var3[i]+0.01f;
      float Kk = sp/(sp+rb[i]+1e-8f);
      float t3n_ = t3[i] + Kk*(zb[i]-t3[i]);
      float v3n = (1.f-Kk)*sp;
      t3[i]=t3n_; var3[i]=v3n;
      t3traj[((size_t)(g+1)*16+b)*128+n]    = bf16_rne(t3n_);
      t3traj[((size_t)(g+1)*16+b)*128+64+n] = bf16_rne(v3n);
    }
    __syncthreads();
  }
}

// ================= fused phase kernels =================

// F1: all input conversions, fragment packs, window means, bias folds (leaves)
__global__ __launch_bounds__(256) void k_f1(
    const float* __restrict__ x, unsigned short* __restrict__ xtb,
    const float* __restrict__ w_t1r, unsigned short* __restrict__ w_t1r_bf,
    const float* __restrict__ w_t2r, unsigned short* __restrict__ w_t2r_bf,
    const float* __restrict__ w_t3r, unsigned short* __restrict__ w_t3r_bf,
    const float* __restrict__ w_t1g, const float* __restrict__ w_t1c,
    unsigned short* __restrict__ wgc1f, unsigned short* __restrict__ wg2f,
    unsigned short* __restrict__ wc2f,
    const float* __restrict__ w_t2v, unsigned short* __restrict__ wtvf,
    const float* __restrict__ w_b21, unsigned short* __restrict__ wb21f,
    const float* __restrict__ w_fuse, unsigned short* __restrict__ wf1f,
    unsigned short* __restrict__ wf2f, unsigned short* __restrict__ wf3f,
    const float* __restrict__ w_t3o, unsigned short* __restrict__ w3of,
    const float* __restrict__ w_t3n, unsigned short* __restrict__ w3nf,
    unsigned short* __restrict__ bm,
    const float* __restrict__ b_fuse, const float* __restrict__ b_t1r,
    const float* __restrict__ b_t2r, const float* __restrict__ b_t3r,
    float* __restrict__ bconst,
    const float* __restrict__ b_t3o, const float* __restrict__ b_t3n,
    float* __restrict__ b2o, float* __restrict__ b2n,
    const float* __restrict__ b_t1g, const float* __restrict__ b_t1c,
    float* __restrict__ bgc){
  int blk = blockIdx.x, tid = threadIdx.x;
  if (blk < 1024){                                    // xtb transpose-convert
    for (int i=0;i<16;i++){
      int r = blk*16 + i; int b = r & 15, t = r >> 4; int d = tid*4;
      float4 v = *(const float4*)(x + ((size_t)b*T_ + t)*D_ + d);
      ushort4 o; o.x=bf16_rne(v.x); o.y=bf16_rne(v.y); o.z=bf16_rne(v.z); o.w=bf16_rne(v.w);
      *(ushort4*)(xtb + (size_t)r*D_ + d) = o;
    }
  } else if (blk < 1280){ dev_conv4(w_t1r, w_t1r_bf, (blk-1024)*256 + tid); }
  else if (blk < 1408){ dev_conv4(w_t2r, w_t2r_bf, (blk-1280)*256 + tid); }
  else if (blk < 1536){ dev_conv4(w_t3r, w_t3r_bf, (blk-1408)*256 + tid); }
  else if (blk < 1664){ dev_fragprep(w_t1g, 0, 32, 256, wgc1f,          (blk-1536)*256 + tid); }
  else if (blk < 1792){ dev_fragprep(w_t1c, 0, 32, 256, wgc1f + 262144, (blk-1664)*256 + tid); }
  else if (blk < 1824){ dev_fragprep(w_t1g, 1024, 8, 256, wg2f, (blk-1792)*256 + tid); }
  else if (blk < 1856){ dev_fragprep(w_t1c, 1024, 8, 256, wc2f, (blk-1824)*256 + tid); }
  else if (blk < 1920){ dev_fragprep(w_t2v, 0, 32, 128, wtvf, (blk-1856)*256 + tid); }
  else if (blk < 1936){ dev_fragprep(w_b21, 0, 4, 256, wb21f, (blk-1920)*256 + tid); }
  else if (blk < 2448){ dev_fragprep(w_fuse, 0,    32, 1024, wf1f, (blk-1936)*256 + tid); }
  else if (blk < 2960){ dev_fragprep(w_fuse, 1024, 32, 1024, wf2f, (blk-2448)*256 + tid); }
  else if (blk < 3472){ dev_fragprep(w_fuse, 2048, 32, 1024, wf3f, (blk-2960)*256 + tid); }
  else if (blk < 3504){ dev_fragprep(w_t3o, 0, 32, 64, w3of, (blk-3472)*256 + tid); }
  else if (blk < 3536){ dev_fragprep(w_t3n, 0, 32, 64, w3nf, (blk-3504)*256 + tid); }
  else if (blk < 4560){ dev_bm(x, bm, blk-3536, tid); }
  else if (blk < 4576){ dev_bconst(w_fuse, b_fuse, b_t1r, b_t2r, b_t3r, bconst, blk-4560, tid); }
  else if (blk < 4577){ dev_b2(b_t2r, w_t3o, b_t3o, w_t3n, b_t3n, b2o, b2n, tid); }
  else { bgc[tid] = b_t1g[tid]; bgc[256+tid] = b_t1c[tid]; }
}

// F2: all first-level GEMMs (P combined g|c, v, weight folds) + beta
__global__ __launch_bounds__(256) void k_f2(
    const unsigned short* __restrict__ xtb, const unsigned short* __restrict__ wgc1f,
    const float* __restrict__ bgc, float* __restrict__ P,
    const unsigned short* __restrict__ bm, const unsigned short* __restrict__ wtvf,
    const float* __restrict__ b_t2v, float* __restrict__ v,
    const unsigned short* __restrict__ w_t1r_bf, const unsigned short* __restrict__ wf1f,
    float* __restrict__ wr1f,
    const unsigned short* __restrict__ w_t2r_bf, const unsigned short* __restrict__ wf2f,
    float* __restrict__ wr2f,
    const unsigned short* __restrict__ w_t3r_bf, const unsigned short* __restrict__ wf3f,
    float* __restrict__ wr3f,
    const unsigned short* __restrict__ w3of, float* __restrict__ w2o,
    const unsigned short* __restrict__ w3nf, float* __restrict__ w2n,
    const float* __restrict__ w_t2b, const float* __restrict__ b_t2b,
    float* __restrict__ beta){
  int blk = blockIdx.x, tid = threadIdx.x;
  if (blk < 2048){ int r = blk;        dev_gemm(16384, 1024, xtb, 1024, wgc1f, bgc, 0, P, 512, r&7, r>>3, tid, 64); }
  else if (blk < 2080){ int r = blk-2048; dev_gemm(1024, 1024, bm, 1024, wtvf, b_t2v, 0, v, 128, r&1, r>>1, tid, 64); }
  else if (blk < 2144){ int r = blk-2080; dev_gemm(256, 1024, w_t1r_bf, 1024, wf1f, nullptr, 0, wr1f, 1024, r&15, r>>4, tid, 64); }
  else if (blk < 2176){ int r = blk-2144; dev_gemm(128, 1024, w_t2r_bf, 1024, wf2f, nullptr, 0, wr2f, 1024, r&15, r>>4, tid, 64); }
  else if (blk < 2208){ int r = blk-2176; dev_gemm(128, 1024, w_t3r_bf, 1024, wf3f, nullptr, 0, wr3f, 1024, r&15, r>>4, tid, 64); }
  else if (blk < 2210){ int r = blk-2208; dev_gemm(128, 1024, w_t2r_bf, 1024, w3of, nullptr, 0, w2o, 64, 0, r, tid, 64); }
  else if (blk < 2212){ int r = blk-2210; dev_gemm(128, 1024, w_t2r_bf, 1024, w3nf, nullptr, 0, w2n, 64, 0, r, tid, 64); }
  else {                                              // beta: 256 blocks x 4 rows
    int rel = blk-2212;
    int r = rel*4 + (tid>>6), l = tid&63;
    float s = 0.f;
    for (int d=l; d<D_; d+=64) s += bf16_tof(bm[(size_t)r*D_+d]) * w_t2b[d];
    #pragma unroll
    for (int off=32; off; off>>=1) s += __shfl_down(s, off);
    if (l==0) beta[r] = fsig(s + b_t2b[0]);
  }
}

// F3: folded-weight fragment packs + tier2/3 trajectory (1024 threads)
__global__ __launch_bounds__(1024) void k_f3(
    const float* __restrict__ wr1f, unsigned short* __restrict__ wr1ff,
    const float* __restrict__ wr2f, unsigned short* __restrict__ wr2ff,
    const float* __restrict__ wr3f, unsigned short* __restrict__ wr3ff,
    const float* __restrict__ v, const float* __restrict__ beta,
    const float* __restrict__ w_b32, const float* __restrict__ b_b32,
    const float* __restrict__ w2o, const float* __restrict__ b2o,
    const float* __restrict__ w2n, const float* __restrict__ b2n,
    unsigned short* __restrict__ t2traj, unsigned short* __restrict__ t3traj){
  int blk = blockIdx.x, tid = threadIdx.x;
  if (blk < 32){ dev_fragprep(wr1f, 0, 8, 1024, wr1ff, blk*1024 + tid); }
  else if (blk < 48){ dev_fragprep(wr2f, 0, 4, 1024, wr2ff, (blk-32)*1024 + tid); }
  else if (blk < 64){ dev_fragprep(wr3f, 0, 4, 1024, wr3ff, (blk-48)*1024 + tid); }
  else { dev_traj(v, beta, w_b32, b_b32, w2o, b2o, w2n, b2n, t2traj, t3traj, tid); }
}

// F4: b21seg GEMM only (true dependency of k_recur)
__global__ __launch_bounds__(256) void k_f4(
    const unsigned short* __restrict__ t2traj, const unsigned short* __restrict__ wb21f,
    const float* __restrict__ b_b21, float* __restrict__ b21seg){
  int blk = blockIdx.x, tid = threadIdx.x;
  dev_gemm(1040, 128, t2traj, 128, wb21f, b_b21, 1, b21seg, 256, blk&3, blk>>2, tid, 64);
}

// ---------------- tier1 GRU recurrence (8-wave r5 structure) + co-run GEMMs ----------------
// Blocks 0-15: recurrence, one block per batch row, 8 waves (2/SIMD).
// Blocks 16-159: f2seg GEMM. Blocks 160-191: f3seg GEMM (no recur dependency).
__global__ __launch_bounds__(512) void k_recur(
    const float* __restrict__ P,   // [16384][512]: cols 0-255 gate, 256-511 cand
    const float* __restrict__ b21, // [65][16][256]
    const unsigned short* __restrict__ Wg2f, const unsigned short* __restrict__ Wc2f,
    unsigned short* __restrict__ traj,
    const unsigned short* __restrict__ t2traj, const unsigned short* __restrict__ wr2ff,
    float* __restrict__ f2seg,
    const unsigned short* __restrict__ t3traj, const unsigned short* __restrict__ wr3ff,
    float* __restrict__ f3seg){
  __shared__ unsigned short sbuf[2][256];
  int blk = blockIdx.x, tid = threadIdx.x;
  if (blk >= 16){
    int rel = blk - 16;
    if (rel < 144) dev_gemm(1040, 128, t2traj, 128, wr2ff, nullptr, 0, f2seg, 1024, rel&15, rel>>4, tid, 128);
    else { rel -= 144;
           dev_gemm(144,  128, t3traj, 128, wr3ff, nullptr, 0, f3seg, 1024, rel&15, rel>>4, tid, 128); }
    return;
  }
  int b = blk;
  int w = tid>>6, l = tid&63;
  int hi = l>>4, cl = l&15;
  const s16x8* Bg = (const s16x8*)Wg2f;
  const s16x8* Bc = (const s16x8*)Wc2f;
  s16x8 bg0[8], bg1[8], bc0[8], bc1[8];
  #pragma unroll
  for (int kt=0;kt<8;kt++){
    bg0[kt] = Bg[((size_t)(2*w)*8  +kt)*64 + l];
    bg1[kt] = Bg[((size_t)(2*w+1)*8+kt)*64 + l];
    bc0[kt] = Bc[((size_t)(2*w)*8  +kt)*64 + l];
    bc1[kt] = Bc[((size_t)(2*w+1)*8+kt)*64 + l];
  }
  bool owner = (hi < 2);
  int nt = 2*w + hi;
  int n  = nt*16 + cl;
  if (!owner) n = 2*w*16 + cl;
  float t1b = 0.f;
  float pgN=0.f, pcN=0.f, bbN=0.f;
  if (owner){
    bbN = b21[((size_t)b)*256 + n];   // seg 0 (consumed at t=0)
    t1b = bbN;                        // tier1=0 + bias21 (state entering t=0)
    pgN = P[((size_t)b)*512 + n];
    pcN = P[((size_t)b)*512 + 256 + n];
    sbuf[0][n] = bf16_rne(t1b);
  }
  asm volatile("s_waitcnt lgkmcnt(0)\ns_barrier" ::: "memory");
  for (int t=0;t<1024;t++){
    float pg = pgN, pc = pcN, bb = bbN;
    int tn = (t+1 < 1024) ? (t+1) : 1023;
    if (owner){
      pgN = P[((size_t)(tn*16+b))*512 + n];
      pcN = P[((size_t)(tn*16+b))*512 + 256 + n];
      bbN = b21[(((size_t)((t+2)>>4))*16 + b)*256 + n];   // seg for step t+1's update
    }
    const unsigned short* sb = sbuf[t&1];
    f32x4 z = {0.f,0.f,0.f,0.f};
    f32x4 ag0=z, ag1=z, ac0=z, ac1=z;
    #pragma unroll
    for (int kt=0;kt<8;kt++){
      s16x8 a = *(const s16x8*)(sb + kt*32 + hi*8);
      ag0 = MFMA(a, bg0[kt], ag0);
      ag1 = MFMA(a, bg1[kt], ag1);
      ac0 = MFMA(a, bc0[kt], ac0);
      ac1 = MFMA(a, bc1[kt], ac1);
    }
    if (owner){
      float gacc = (hi==0)? ag0[0] : ag1[0];
      float cacc = (hi==0)? ac0[0] : ac1[0];
      float g = fsig(gacc + pg);
      float c = ftanh(cacc + pc);
      float t1n = g*t1b + (1.f-g)*c;
      traj[((size_t)(t*16+b))*256 + n] = bf16_rne(t1n);
      t1b = t1n + bb;
      sbuf[(t+1)&1][n] = bf16_rne(t1b);
    }
    asm volatile("s_waitcnt lgkmcnt(0)\ns_barrier" ::: "memory");
  }
}

// ---------------- fused1 GEMM + segment adds + LayerNorm + output ----------------
__global__ __launch_bounds__(1024) void k_final(
    const unsigned short* __restrict__ traj, const unsigned short* __restrict__ Bf,
    const float* __restrict__ bconst, const float* __restrict__ f2seg, const float* __restrict__ f3seg,
    const float* __restrict__ ln_g, const float* __restrict__ ln_b, float* __restrict__ out){
  __shared__ float buf[16*1024];
  __shared__ float mu[16];
  __shared__ float rs[16];
  int t = blockIdx.x, tid = threadIdx.x, w = tid>>6, l = tid&63;
  const unsigned short* Ab = traj + ((size_t)t*16 + (l&15))*256 + (l>>4)*8;
  const s16x8* Bp = (const s16x8*)Bf;
  f32x4 z = {0.f,0.f,0.f,0.f};
  f32x4 ac[4]; ac[0]=z; ac[1]=z; ac[2]=z; ac[3]=z;
  #pragma unroll
  for (int kt=0;kt<8;kt++){
    s16x8 a = *(const s16x8*)(Ab + kt*32);
    #pragma unroll
    for (int i=0;i<4;i++){
      int nt = w*4+i;
      ac[i] = MFMA(a, Bp[((size_t)nt*8+kt)*64+l], ac[i]);
    }
  }
  int tc = t+1, s2 = tc>>4, s3 = tc>>7;
  int r0 = (l>>4)*4, cl = l&15;
  #pragma unroll
  for (int i=0;i<4;i++){
    int col = (w*4+i)*16+cl;
    #pragma unroll
    for (int j=0;j<4;j++){
      int b = r0+j;
      buf[b*1024+col] = ac[i][j] + bconst[col]
        + f2seg[((size_t)s2*16+b)*1024+col] + f3seg[((size_t)s3*16+b)*1024+col];
    }
  }
  __syncthreads();
  {
    float s=0.f, q=0.f;
    #pragma unroll
    for (int i=0;i<16;i++){ float xv = buf[w*1024 + l + 64*i]; s+=xv; q+=xv*xv; }
    #pragma unroll
    for (int off=32;off;off>>=1){ s += __shfl_down(s,off); q += __shfl_down(q,off); }
    if (l==0){ float m = s*(1.f/1024.f); float var = q*(1.f/1024.f) - m*m; mu[w]=m; rs[w]=rsqrtf(var+1e-5f); }
  }
  __syncthreads();
  {
    int b = tid>>6, d0 = tid&63;
    float m = mu[b], r = rs[b];
    size_t ob = ((size_t)b*1024 + t)*1024;
    #pragma unroll
    for (int i=0;i<16;i++){
      int d = d0 + 64*i;
      out[ob + d] = (buf[b*1024+d]-m)*r*ln_g[d] + ln_b[d];
    }
  }
}

// ---------------- launcher ----------------
extern "C" void kernel_launch(void* const* d_in, const int* in_sizes, int n_in,
                              void* d_out, int out_size, void* d_ws, size_t ws_size,
                              hipStream_t stream){
  const float* x     = (const float*)d_in[0];
  const float* w_t1g = (const float*)d_in[1];
  const float* b_t1g = (const float*)d_in[2];
  const float* w_t1c = (const float*)d_in[3];
  const float* b_t1c = (const float*)d_in[4];
  const float* w_t1r = (const float*)d_in[5];
  const float* b_t1r = (const float*)d_in[6];
  const float* w_t2v = (const float*)d_in[7];
  const float* b_t2v = (const float*)d_in[8];
  const float* w_t2b = (const float*)d_in[9];
  const float* b_t2b = (const float*)d_in[10];
  const float* w_t2r = (const float*)d_in[11];
  const float* b_t2r = (const float*)d_in[12];
  const float* w_t3o = (const float*)d_in[13];
  const float* b_t3o = (const float*)d_in[14];
  const float* w_t3n = (const float*)d_in[15];
  const float* b_t3n = (const float*)d_in[16];
  const float* w_t3r = (const float*)d_in[17];
  const float* b_t3r = (const float*)d_in[18];
  const float* w_b32 = (const float*)d_in[19];
  const float* b_b32 = (const float*)d_in[20];
  const float* w_b21 = (const float*)d_in[21];
  const float* b_b21 = (const float*)d_in[22];
  const float* w_fuse= (const float*)d_in[23];
  const float* b_fuse= (const float*)d_in[24];
  const float* ln_g  = (const float*)d_in[25];
  const float* ln_b  = (const float*)d_in[26];
  float* out = (float*)d_out;
  (void)in_sizes; (void)n_in; (void)out_size; (void)ws_size;

  char* base = (char*)d_ws;
  size_t off = 0;
  auto alloc = [&](size_t bytes) -> void* {
    void* p = base + off;
    off += (bytes + 255) & ~(size_t)255;
    return p;
  };
  unsigned short* xtb   = (unsigned short*)alloc((size_t)B_*T_*D_*2);
  float* P              = (float*)alloc((size_t)B_*T_*512*4);
  unsigned short* traj1 = (unsigned short*)alloc((size_t)B_*T_*256*2);
  unsigned short* bm    = (unsigned short*)alloc((size_t)1024*1024*2);
  float* v      = (float*)alloc((size_t)1024*128*4);
  float* beta   = (float*)alloc(1024*4);
  float* wr1f   = (float*)alloc((size_t)256*1024*4);
  float* wr2f   = (float*)alloc((size_t)128*1024*4);
  float* wr3f   = (float*)alloc((size_t)128*1024*4);
  float* w2o    = (float*)alloc(128*64*4);
  float* w2n    = (float*)alloc(128*64*4);
  float* b2o    = (float*)alloc(64*4);
  float* b2n    = (float*)alloc(64*4);
  float* bconst = (float*)alloc(1024*4);
  float* bgc    = (float*)alloc(512*4);
  unsigned short* t2traj = (unsigned short*)alloc((size_t)1040*128*2);
  unsigned short* t3traj = (unsigned short*)alloc((size_t)144*128*2);
  float* b21seg = (float*)alloc((size_t)1040*256*4);
  float* f2seg  = (float*)alloc((size_t)1040*1024*4);
  float* f3seg  = (float*)alloc((size_t)144*1024*4);
  unsigned short* w_t1r_bf = (unsigned short*)alloc((size_t)256*1024*2);
  unsigned short* w_t2r_bf = (unsigned short*)alloc((size_t)128*1024*2);
  unsigned short* w_t3r_bf = (unsigned short*)alloc((size_t)128*1024*2);
  unsigned short* wgc1f = (unsigned short*)alloc((size_t)1024*512*2);
  unsigned short* wg2f  = (unsigned short*)alloc((size_t)256*256*2);
  unsigned short* wc2f  = (unsigned short*)alloc((size_t)256*256*2);
  unsigned short* wtvf  = (unsigned short*)alloc((size_t)1024*128*2);
  unsigned short* wb21f = (unsigned short*)alloc((size_t)128*256*2);
  unsigned short* wf1f  = (unsigned short*)alloc((size_t)1024*1024*2);
  unsigned short* wf2f  = (unsigned short*)alloc((size_t)1024*1024*2);
  unsigned short* wf3f  = (unsigned short*)alloc((size_t)1024*1024*2);
  unsigned short* w3of  = (unsigned short*)alloc((size_t)1024*64*2);
  unsigned short* w3nf  = (unsigned short*)alloc((size_t)1024*64*2);
  unsigned short* wr1ff = (unsigned short*)alloc((size_t)256*1024*2);
  unsigned short* wr2ff = (unsigned short*)alloc((size_t)128*1024*2);
  unsigned short* wr3ff = (unsigned short*)alloc((size_t)128*1024*2);

  k_f1<<<dim3(4578), dim3(256), 0, stream>>>(
      x, xtb, w_t1r, w_t1r_bf, w_t2r, w_t2r_bf, w_t3r, w_t3r_bf,
      w_t1g, w_t1c, wgc1f, wg2f, wc2f, w_t2v, wtvf, w_b21, wb21f,
      w_fuse, wf1f, wf2f, wf3f, w_t3o, w3of, w_t3n, w3nf, bm,
      b_fuse, b_t1r, b_t2r, b_t3r, bconst, b_t3o, b_t3n, b2o, b2n,
      b_t1g, b_t1c, bgc);
  k_f2<<<dim3(2468), dim3(256), 0, stream>>>(
      xtb, wgc1f, bgc, P, bm, wtvf, b_t2v, v,
      w_t1r_bf, wf1f, wr1f, w_t2r_bf, wf2f, wr2f, w_t3r_bf, wf3f, wr3f,
      w3of, w2o, w3nf, w2n, w_t2b, b_t2b, beta);
  k_f3<<<dim3(65), dim3(1024), 0, stream>>>(
      wr1f, wr1ff, wr2f, wr2ff, wr3f, wr3ff,
      v, beta, w_b32, b_b32, w2o, b2o, w2n, b2n, t2traj, t3traj);
  k_f4<<<dim3(68), dim3(256), 0, stream>>>(t2traj, wb21f, b_b21, b21seg);
  k_recur<<<dim3(192), dim3(512), 0, stream>>>(
      P, b21seg, wg2f, wc2f, traj1,
      t2traj, wr2ff, f2seg, t3traj, wr3ff, f3seg);
  k_final<<<dim3(1024), dim3(1024), 0, stream>>>(traj1, wr1ff, bconst, f2seg, f3seg, ln_g, ln_b, out);
}

// Round 10
// 1099.543 us; speedup vs baseline: 1.0013x; 1.0013x over previous
//
#include <hip/hip_runtime.h>

#define D_ 1024
#define T_ 1024
#define B_ 16

typedef short s16x8 __attribute__((ext_vector_type(8)));
typedef float f32x4 __attribute__((ext_vector_type(4)));

__device__ __forceinline__ unsigned short bf16_rne(float f){
  unsigned int u = __builtin_bit_cast(unsigned int, f);
  u += 0x7FFFu + ((u >> 16) & 1u);
  return (unsigned short)(u >> 16);
}
__device__ __forceinline__ float bf16_tof(unsigned short h){
  unsigned int u = ((unsigned int)h) << 16;
  return __builtin_bit_cast(float, u);
}
__device__ __forceinline__ float fsig(float x){ return 1.0f/(1.0f+__expf(-x)); }
__device__ __forceinline__ float ftanh(float x){ return 2.0f*fsig(2.0f*x)-1.0f; }

// MFMA wrapper robust to builtin operand type (short8 vs __bf16 x8)
template <typename V>
__device__ __forceinline__ auto mfma_try(V a, V b, f32x4 c, int)
    -> decltype(__builtin_amdgcn_mfma_f32_16x16x32_bf16(a, b, c, 0, 0, 0)) {
  return __builtin_amdgcn_mfma_f32_16x16x32_bf16(a, b, c, 0, 0, 0);
}
template <typename V>
__device__ __forceinline__ f32x4 mfma_try(V a, V b, f32x4 c, long) {
  typedef __bf16 bf16x8 __attribute__((ext_vector_type(8)));
  return __builtin_amdgcn_mfma_f32_16x16x32_bf16(
      __builtin_bit_cast(bf16x8, a), __builtin_bit_cast(bf16x8, b), c, 0, 0, 0);
}
__device__ __forceinline__ f32x4 MFMA(s16x8 a, s16x8 b, f32x4 c){
  return mfma_try(a, b, c, 0);
}

// ================= device task bodies =================

__device__ __forceinline__ void dev_conv4(const float* __restrict__ s,
                                          unsigned short* __restrict__ d, int g){
  float4 v = *(const float4*)(s + (size_t)g*4);
  ushort4 o; o.x=bf16_rne(v.x); o.y=bf16_rne(v.y); o.z=bf16_rne(v.z); o.w=bf16_rne(v.w);
  *(ushort4*)(d + (size_t)g*4) = o;
}

// pack f32 row-major weight [rowOff+K, Nsrc] into MFMA B-fragment order (bf16)
// slot = ((nt*KT + kt)*64 + lane) holds B[kt*32+(lane>>4)*8+j][nt*16+(lane&15)]
__device__ __forceinline__ void dev_fragprep(const float* __restrict__ w, int rowOff,
                                             int KT, int Nsrc,
                                             unsigned short* __restrict__ dst, int slot){
  int lane = slot & 63; int tmp = slot >> 6; int kt = tmp % KT; int nt = tmp / KT;
  int kbase = kt*32 + (lane>>4)*8; int col = nt*16 + (lane&15);
  unsigned short* o = dst + (size_t)slot*8;
  #pragma unroll
  for (int j=0;j<8;j++) o[j] = bf16_rne(w[(size_t)(rowOff + kbase + j)*Nsrc + col]);
}

// window means at the 64 do2 points
__device__ __forceinline__ void dev_bm(const float* __restrict__ x,
                                       unsigned short* __restrict__ bm, int blk, int tid){
  int e = blk >> 4; int b = blk & 15;
  int tc = 16*(e+1); int hi = tc-2; int lo = tc-33; if (lo < 0) lo = 0;
  const float* xb = x + (size_t)b*T_*D_;
  for (int d = tid; d < D_; d += 256){
    float s = 0.f;
    for (int ss = lo; ss <= hi; ++ss) s += xb[(size_t)ss*D_ + d];
    bm[((size_t)(e*16+b))*D_ + d] = bf16_rne(s * (1.0f/32.0f));
  }
}

__device__ __forceinline__ void dev_bconst(const float* __restrict__ wf, const float* __restrict__ bf,
                                           const float* __restrict__ b1, const float* __restrict__ b2,
                                           const float* __restrict__ b3, float* __restrict__ bc,
                                           int blk, int tid){
  __shared__ float part[4][64];
  int n = blk*64 + (tid&63);
  int sl = tid>>6;
  float s = 0.f;
  for (int k=sl*256; k<(sl+1)*256; ++k){
    s += b1[k]*wf[(size_t)k*1024+n] + b2[k]*wf[(size_t)(1024+k)*1024+n] + b3[k]*wf[(size_t)(2048+k)*1024+n];
  }
  part[sl][tid&63] = s; __syncthreads();
  if (sl==0) bc[n] = bf[n] + part[0][tid] + part[1][tid] + part[2][tid] + part[3][tid];
}

__device__ __forceinline__ void dev_b2(const float* __restrict__ b_t2r, const float* __restrict__ w3o,
                                       const float* __restrict__ b3o, const float* __restrict__ w3n,
                                       const float* __restrict__ b3n, float* __restrict__ b2o,
                                       float* __restrict__ b2n, int tid){
  __shared__ float part[2][128];
  int idx = tid & 127; int sl = tid >> 7;
  int mat = idx>>6, n = idx&63;
  const float* w = mat ? w3n : w3o;
  float s = 0.f;
  for (int k=sl*512; k<(sl+1)*512; ++k) s += b_t2r[k]*w[(size_t)k*64+n];
  part[sl][idx] = s; __syncthreads();
  if (sl==0){
    float r = part[0][idx] + part[1][idx] + (mat? b3n[n] : b3o[n]);
    if (mat) b2n[n] = r; else b2o[n] = r;
  }
}

// generic bf16 MFMA GEMM tile: block covers rows [rb*rows, +rows) x cols [cb*64, +64)
// rows = 16 * (#waves in group)
__device__ __forceinline__ void dev_gemm(int M, int K,
    const unsigned short* __restrict__ A, int lda,
    const unsigned short* __restrict__ Bf,
    const float* __restrict__ bias, int act,
    float* __restrict__ C, int ldc, int cb, int rb, int tid, int rows){
  int KT = K >> 5;
  int w = tid >> 6, l = tid & 63;
  int rbase = rb*rows + w*16;
  int arow = rbase + (l & 15); if (arow >= M) arow = M-1;
  const unsigned short* Aptr = A + (size_t)arow*lda + ((l>>4)*8);
  const s16x8* B0 = (const s16x8*)Bf + ((size_t)(cb*4+0)*KT)*64 + l;
  const s16x8* B1 = (const s16x8*)Bf + ((size_t)(cb*4+1)*KT)*64 + l;
  const s16x8* B2 = (const s16x8*)Bf + ((size_t)(cb*4+2)*KT)*64 + l;
  const s16x8* B3 = (const s16x8*)Bf + ((size_t)(cb*4+3)*KT)*64 + l;
  f32x4 z = {0.f,0.f,0.f,0.f};
  f32x4 acc0=z, acc1=z, acc2=z, acc3=z;
  for (int kt=0; kt<KT; ++kt){
    s16x8 a = *(const s16x8*)(Aptr + (size_t)kt*32);
    acc0 = MFMA(a, B0[(size_t)kt*64], acc0);
    acc1 = MFMA(a, B1[(size_t)kt*64], acc1);
    acc2 = MFMA(a, B2[(size_t)kt*64], acc2);
    acc3 = MFMA(a, B3[(size_t)kt*64], acc3);
  }
  int r0 = (l>>4)*4;
  #pragma unroll
  for (int i=0;i<4;i++){
    f32x4 acc = i==0?acc0 : i==1?acc1 : i==2?acc2 : acc3;
    int col = (cb*4+i)*16 + (l&15);
    float bs = bias ? bias[col] : 0.0f;
    #pragma unroll
    for (int j=0;j<4;j++){
      int row = rbase + r0 + j;
      if (row < M){
        float vv = acc[j] + bs;
        if (act==1) vv = ftanh(vv);
        C[(size_t)row*ldc + col] = vv;
      }
    }
  }
}

// tier2/tier3 trajectory (sequential, tiny) — 1024 threads.
// bias32 hoisted per 8-event group (tier3 frozen within group).
__device__ void dev_traj(
    const float* __restrict__ v, const float* __restrict__ beta,
    const float* __restrict__ w_b32, const float* __restrict__ b_b32,
    const float* __restrict__ w2o, const float* __restrict__ b2o,
    const float* __restrict__ w2n, const float* __restrict__ b2n,
    unsigned short* __restrict__ t2traj, unsigned short* __restrict__ t3traj, int tid){
  __shared__ float t2[16*128];
  __shared__ float t3[16*64];
  __shared__ float var3[16*64];
  __shared__ float zb[16*64];
  __shared__ float rb[16*64];
  __shared__ float b32[16*128];
  for (int i=tid;i<2048;i+=1024){ t2[i]=0.f; t2traj[i]=0; }
  for (int i=tid;i<1024;i+=1024){
    int b=i>>6, n=i&63;
    t3[i]=0.f; var3[i]=1.f;
    t3traj[(size_t)b*128 + n] = 0;
    t3traj[(size_t)b*128 + 64 + n] = bf16_rne(1.f);
  }
  __syncthreads();
  for (int g=0; g<8; ++g){
    for (int i=tid;i<2048;i+=1024){
      int b=i>>7, n=i&127;
      float s=b_b32[n];
      for (int j=0;j<64;j++) s += t3[b*64+j]*w_b32[j*128+n];
      b32[i] = ftanh(s);
    }
    __syncthreads();
    for (int kk=0; kk<8; ++kk){
      int k = g*8 + kk + 1;
      for (int i=tid;i<2048;i+=1024){
        int b=i>>7, n=i&127;
        float t2b = t2[i] + b32[i];
        float bt = beta[(k-1)*16+b];
        float nv = t2b + bt*(v[(size_t)((k-1)*16+b)*128+n] - t2b);
        t2[i]=nv;
        t2traj[((size_t)k*16+b)*128+n] = bf16_rne(nv);
      }
    }
    __syncthreads();
    for (int i=tid;i<2048;i+=1024){
      int mat=i>>10, b=(i>>6)&15, n=i&63;
      const float* w = mat? w2n : w2o;
      float s = mat? b2n[n] : b2o[n];
      for (int j=0;j<128;j++) s += t2[b*128+j]*w[j*64+n];
      if (mat){ float r = (s>20.f)? s : log1pf(__expf(s)); rb[b*64+n]=r+0.01f; }
      else zb[b*64+n]=s;
    }
    __syncthreads();
    for (int i=tid;i<1024;i+=1024){
      int b=i>>6, n=i&63;
      float sp = 0.99f*var3[i]+0.01f;
      float Kk = sp/(sp+rb[i]+1e-8f);
      float t3n_ = t3[i] + Kk*(zb[i]-t3[i]);
      float v3n = (1.f-Kk)*sp;
      t3[i]=t3n_; var3[i]=v3n;
      t3traj[((size_t)(g+1)*16+b)*128+n]    = bf16_rne(t3n_);
      t3traj[((size_t)(g+1)*16+b)*128+64+n] = bf16_rne(v3n);
    }
    __syncthreads();
  }
}

// ================= fused phase kernels =================

// F1: all input conversions, fragment packs, window means, bias folds (leaves)
__global__ __launch_bounds__(256) void k_f1(
    const float* __restrict__ x, unsigned short* __restrict__ xtb,
    const float* __restrict__ w_t1r, unsigned short* __restrict__ w_t1r_bf,
    const float* __restrict__ w_t2r, unsigned short* __restrict__ w_t2r_bf,
    const float* __restrict__ w_t3r, unsigned short* __restrict__ w_t3r_bf,
    const float* __restrict__ w_t1g, const float* __restrict__ w_t1c,
    unsigned short* __restrict__ wgc1f, unsigned short* __restrict__ wg2f,
    unsigned short* __restrict__ wc2f,
    const float* __restrict__ w_t2v, unsigned short* __restrict__ wtvf,
    const float* __restrict__ w_b21, unsigned short* __restrict__ wb21f,
    const float* __restrict__ w_fuse, unsigned short* __restrict__ wf1f,
    unsigned short* __restrict__ wf2f, unsigned short* __restrict__ wf3f,
    const float* __restrict__ w_t3o, unsigned short* __restrict__ w3of,
    const float* __restrict__ w_t3n, unsigned short* __restrict__ w3nf,
    unsigned short* __restrict__ bm,
    const float* __restrict__ b_fuse, const float* __restrict__ b_t1r,
    const float* __restrict__ b_t2r, const float* __restrict__ b_t3r,
    float* __restrict__ bconst,
    const float* __restrict__ b_t3o, const float* __restrict__ b_t3n,
    float* __restrict__ b2o, float* __restrict__ b2n,
    const float* __restrict__ b_t1g, const float* __restrict__ b_t1c,
    float* __restrict__ bgc){
  int blk = blockIdx.x, tid = threadIdx.x;
  if (blk < 1024){                                    // xtb transpose-convert
    for (int i=0;i<16;i++){
      int r = blk*16 + i; int b = r & 15, t = r >> 4; int d = tid*4;
      float4 v = *(const float4*)(x + ((size_t)b*T_ + t)*D_ + d);
      ushort4 o; o.x=bf16_rne(v.x); o.y=bf16_rne(v.y); o.z=bf16_rne(v.z); o.w=bf16_rne(v.w);
      *(ushort4*)(xtb + (size_t)r*D_ + d) = o;
    }
  } else if (blk < 1280){ dev_conv4(w_t1r, w_t1r_bf, (blk-1024)*256 + tid); }
  else if (blk < 1408){ dev_conv4(w_t2r, w_t2r_bf, (blk-1280)*256 + tid); }
  else if (blk < 1536){ dev_conv4(w_t3r, w_t3r_bf, (blk-1408)*256 + tid); }
  else if (blk < 1664){ dev_fragprep(w_t1g, 0, 32, 256, wgc1f,          (blk-1536)*256 + tid); }
  else if (blk < 1792){ dev_fragprep(w_t1c, 0, 32, 256, wgc1f + 262144, (blk-1664)*256 + tid); }
  else if (blk < 1824){ dev_fragprep(w_t1g, 1024, 8, 256, wg2f, (blk-1792)*256 + tid); }
  else if (blk < 1856){ dev_fragprep(w_t1c, 1024, 8, 256, wc2f, (blk-1824)*256 + tid); }
  else if (blk < 1920){ dev_fragprep(w_t2v, 0, 32, 128, wtvf, (blk-1856)*256 + tid); }
  else if (blk < 1936){ dev_fragprep(w_b21, 0, 4, 256, wb21f, (blk-1920)*256 + tid); }
  else if (blk < 2448){ dev_fragprep(w_fuse, 0,    32, 1024, wf1f, (blk-1936)*256 + tid); }
  else if (blk < 2960){ dev_fragprep(w_fuse, 1024, 32, 1024, wf2f, (blk-2448)*256 + tid); }
  else if (blk < 3472){ dev_fragprep(w_fuse, 2048, 32, 1024, wf3f, (blk-2960)*256 + tid); }
  else if (blk < 3504){ dev_fragprep(w_t3o, 0, 32, 64, w3of, (blk-3472)*256 + tid); }
  else if (blk < 3536){ dev_fragprep(w_t3n, 0, 32, 64, w3nf, (blk-3504)*256 + tid); }
  else if (blk < 4560){ dev_bm(x, bm, blk-3536, tid); }
  else if (blk < 4576){ dev_bconst(w_fuse, b_fuse, b_t1r, b_t2r, b_t3r, bconst, blk-4560, tid); }
  else if (blk < 4577){ dev_b2(b_t2r, w_t3o, b_t3o, w_t3n, b_t3n, b2o, b2n, tid); }
  else { bgc[tid] = b_t1g[tid]; bgc[256+tid] = b_t1c[tid]; }
}

// F2: all first-level GEMMs (P combined g|c, v, weight folds) + beta
__global__ __launch_bounds__(256) void k_f2(
    const unsigned short* __restrict__ xtb, const unsigned short* __restrict__ wgc1f,
    const float* __restrict__ bgc, float* __restrict__ P,
    const unsigned short* __restrict__ bm, const unsigned short* __restrict__ wtvf,
    const float* __restrict__ b_t2v, float* __restrict__ v,
    const unsigned short* __restrict__ w_t1r_bf, const unsigned short* __restrict__ wf1f,
    float* __restrict__ wr1f,
    const unsigned short* __restrict__ w_t2r_bf, const unsigned short* __restrict__ wf2f,
    float* __restrict__ wr2f,
    const unsigned short* __restrict__ w_t3r_bf, const unsigned short* __restrict__ wf3f,
    float* __restrict__ wr3f,
    const unsigned short* __restrict__ w3of, float* __restrict__ w2o,
    const unsigned short* __restrict__ w3nf, float* __restrict__ w2n,
    const float* __restrict__ w_t2b, const float* __restrict__ b_t2b,
    float* __restrict__ beta){
  int blk = blockIdx.x, tid = threadIdx.x;
  if (blk < 2048){ int r = blk;        dev_gemm(16384, 1024, xtb, 1024, wgc1f, bgc, 0, P, 512, r&7, r>>3, tid, 64); }
  else if (blk < 2080){ int r = blk-2048; dev_gemm(1024, 1024, bm, 1024, wtvf, b_t2v, 0, v, 128, r&1, r>>1, tid, 64); }
  else if (blk < 2144){ int r = blk-2080; dev_gemm(256, 1024, w_t1r_bf, 1024, wf1f, nullptr, 0, wr1f, 1024, r&15, r>>4, tid, 64); }
  else if (blk < 2176){ int r = blk-2144; dev_gemm(128, 1024, w_t2r_bf, 1024, wf2f, nullptr, 0, wr2f, 1024, r&15, r>>4, tid, 64); }
  else if (blk < 2208){ int r = blk-2176; dev_gemm(128, 1024, w_t3r_bf, 1024, wf3f, nullptr, 0, wr3f, 1024, r&15, r>>4, tid, 64); }
  else if (blk < 2210){ int r = blk-2208; dev_gemm(128, 1024, w_t2r_bf, 1024, w3of, nullptr, 0, w2o, 64, 0, r, tid, 64); }
  else if (blk < 2212){ int r = blk-2210; dev_gemm(128, 1024, w_t2r_bf, 1024, w3nf, nullptr, 0, w2n, 64, 0, r, tid, 64); }
  else {                                              // beta: 256 blocks x 4 rows
    int rel = blk-2212;
    int r = rel*4 + (tid>>6), l = tid&63;
    float s = 0.f;
    for (int d=l; d<D_; d+=64) s += bf16_tof(bm[(size_t)r*D_+d]) * w_t2b[d];
    #pragma unroll
    for (int off=32; off; off>>=1) s += __shfl_down(s, off);
    if (l==0) beta[r] = fsig(s + b_t2b[0]);
  }
}

// F3: folded-weight fragment packs + tier2/3 trajectory (1024 threads)
__global__ __launch_bounds__(1024) void k_f3(
    const float* __restrict__ wr1f, unsigned short* __restrict__ wr1ff,
    const float* __restrict__ wr2f, unsigned short* __restrict__ wr2ff,
    const float* __restrict__ wr3f, unsigned short* __restrict__ wr3ff,
    const float* __restrict__ v, const float* __restrict__ beta,
    const float* __restrict__ w_b32, const float* __restrict__ b_b32,
    const float* __restrict__ w2o, const float* __restrict__ b2o,
    const float* __restrict__ w2n, const float* __restrict__ b2n,
    unsigned short* __restrict__ t2traj, unsigned short* __restrict__ t3traj){
  int blk = blockIdx.x, tid = threadIdx.x;
  if (blk < 32){ dev_fragprep(wr1f, 0, 8, 1024, wr1ff, blk*1024 + tid); }
  else if (blk < 48){ dev_fragprep(wr2f, 0, 4, 1024, wr2ff, (blk-32)*1024 + tid); }
  else if (blk < 64){ dev_fragprep(wr3f, 0, 4, 1024, wr3ff, (blk-48)*1024 + tid); }
  else { dev_traj(v, beta, w_b32, b_b32, w2o, b2o, w2n, b2n, t2traj, t3traj, tid); }
}

// F4: b21seg GEMM only (true dependency of k_recur)
__global__ __launch_bounds__(256) void k_f4(
    const unsigned short* __restrict__ t2traj, const unsigned short* __restrict__ wb21f,
    const float* __restrict__ b_b21, float* __restrict__ b21seg){
  int blk = blockIdx.x, tid = threadIdx.x;
  dev_gemm(1040, 128, t2traj, 128, wb21f, b_b21, 1, b21seg, 256, blk&3, blk>>2, tid, 64);
}

// ---------------- tier1 GRU recurrence (8-wave r5 structure) + co-run GEMMs ----------------
// Blocks 0-15: recurrence, one block per batch row, 8 waves (2/SIMD).
// Blocks 16-159: f2seg GEMM. Blocks 160-191: f3seg GEMM (no recur dependency).
__global__ __launch_bounds__(512) void k_recur(
    const float* __restrict__ P,   // [16384][512]: cols 0-255 gate, 256-511 cand
    const float* __restrict__ b21, // [65][16][256]
    const unsigned short* __restrict__ Wg2f, const unsigned short* __restrict__ Wc2f,
    unsigned short* __restrict__ traj,
    const unsigned short* __restrict__ t2traj, const unsigned short* __restrict__ wr2ff,
    float* __restrict__ f2seg,
    const unsigned short* __restrict__ t3traj, const unsigned short* __restrict__ wr3ff,
    float* __restrict__ f3seg){
  __shared__ unsigned short sbuf[2][256];
  int blk = blockIdx.x, tid = threadIdx.x;
  if (blk >= 16){
    int rel = blk - 16;
    if (rel < 144) dev_gemm(1040, 128, t2traj, 128, wr2ff, nullptr, 0, f2seg, 1024, rel&15, rel>>4, tid, 128);
    else { rel -= 144;
           dev_gemm(144,  128, t3traj, 128, wr3ff, nullptr, 0, f3seg, 1024, rel&15, rel>>4, tid, 128); }
    return;
  }
  int b = blk;
  int w = tid>>6, l = tid&63;
  int hi = l>>4, cl = l&15;
  const s16x8* Bg = (const s16x8*)Wg2f;
  const s16x8* Bc = (const s16x8*)Wc2f;
  s16x8 bg0[8], bg1[8], bc0[8], bc1[8];
  #pragma unroll
  for (int kt=0;kt<8;kt++){
    bg0[kt] = Bg[((size_t)(2*w)*8  +kt)*64 + l];
    bg1[kt] = Bg[((size_t)(2*w+1)*8+kt)*64 + l];
    bc0[kt] = Bc[((size_t)(2*w)*8  +kt)*64 + l];
    bc1[kt] = Bc[((size_t)(2*w+1)*8+kt)*64 + l];
  }
  bool owner = (hi < 2);
  int nt = 2*w + hi;
  int n  = nt*16 + cl;
  if (!owner) n = 2*w*16 + cl;
  float t1b = 0.f;
  float pgN=0.f, pcN=0.f, bbN=0.f;
  if (owner){
    bbN = b21[((size_t)b)*256 + n];   // seg 0 (consumed at t=0)
    t1b = bbN;                        // tier1=0 + bias21 (state entering t=0)
    pgN = P[((size_t)b)*512 + n];
    pcN = P[((size_t)b)*512 + 256 + n];
    sbuf[0][n] = bf16_rne(t1b);
  }
  asm volatile("s_waitcnt lgkmcnt(0)\ns_barrier" ::: "memory");
  for (int t=0;t<1024;t++){
    float pg = pgN, pc = pcN, bb = bbN;
    int tn = (t+1 < 1024) ? (t+1) : 1023;
    if (owner){
      pgN = P[((size_t)(tn*16+b))*512 + n];
      pcN = P[((size_t)(tn*16+b))*512 + 256 + n];
      bbN = b21[(((size_t)((t+2)>>4))*16 + b)*256 + n];   // seg for step t+1's update
    }
    const unsigned short* sb = sbuf[t&1];
    f32x4 z = {0.f,0.f,0.f,0.f};
    f32x4 ag0=z, ag1=z, ac0=z, ac1=z;
    #pragma unroll
    for (int kt=0;kt<8;kt++){
      s16x8 a = *(const s16x8*)(sb + kt*32 + hi*8);
      ag0 = MFMA(a, bg0[kt], ag0);
      ag1 = MFMA(a, bg1[kt], ag1);
      ac0 = MFMA(a, bc0[kt], ac0);
      ac1 = MFMA(a, bc1[kt], ac1);
    }
    if (owner){
      float gacc = (hi==0)? ag0[0] : ag1[0];
      float cacc = (hi==0)? ac0[0] : ac1[0];
      float g = fsig(gacc + pg);
      float c = ftanh(cacc + pc);
      float t1n = g*t1b + (1.f-g)*c;
      traj[((size_t)(t*16+b))*256 + n] = bf16_rne(t1n);
      t1b = t1n + bb;
      sbuf[(t+1)&1][n] = bf16_rne(t1b);
    }
    asm volatile("s_waitcnt lgkmcnt(0)\ns_barrier" ::: "memory");
  }
}

// ---------------- fused1 GEMM + segment adds + LayerNorm + output ----------------
__global__ __launch_bounds__(1024) void k_final(
    const unsigned short* __restrict__ traj, const unsigned short* __restrict__ Bf,
    const float* __restrict__ bconst, const float* __restrict__ f2seg, const float* __restrict__ f3seg,
    const float* __restrict__ ln_g, const float* __restrict__ ln_b, float* __restrict__ out){
  __shared__ float buf[16*1024];
  __shared__ float mu[16];
  __shared__ float rs[16];
  int t = blockIdx.x, tid = threadIdx.x, w = tid>>6, l = tid&63;
  const unsigned short* Ab = traj + ((size_t)t*16 + (l&15))*256 + (l>>4)*8;
  const s16x8* Bp = (const s16x8*)Bf;
  f32x4 z = {0.f,0.f,0.f,0.f};
  f32x4 ac[4]; ac[0]=z; ac[1]=z; ac[2]=z; ac[3]=z;
  #pragma unroll
  for (int kt=0;kt<8;kt++){
    s16x8 a = *(const s16x8*)(Ab + kt*32);
    #pragma unroll
    for (int i=0;i<4;i++){
      int nt = w*4+i;
      ac[i] = MFMA(a, Bp[((size_t)nt*8+kt)*64+l], ac[i]);
    }
  }
  int tc = t+1, s2 = tc>>4, s3 = tc>>7;
  int r0 = (l>>4)*4, cl = l&15;
  #pragma unroll
  for (int i=0;i<4;i++){
    int col = (w*4+i)*16+cl;
    #pragma unroll
    for (int j=0;j<4;j++){
      int b = r0+j;
      buf[b*1024+col] = ac[i][j] + bconst[col]
        + f2seg[((size_t)s2*16+b)*1024+col] + f3seg[((size_t)s3*16+b)*1024+col];
    }
  }
  __syncthreads();
  {
    float s=0.f, q=0.f;
    #pragma unroll
    for (int i=0;i<16;i++){ float xv = buf[w*1024 + l + 64*i]; s+=xv; q+=xv*xv; }
    #pragma unroll
    for (int off=32;off;off>>=1){ s += __shfl_down(s,off); q += __shfl_down(q,off); }
    if (l==0){ float m = s*(1.f/1024.f); float var = q*(1.f/1024.f) - m*m; mu[w]=m; rs[w]=rsqrtf(var+1e-5f); }
  }
  __syncthreads();
  {
    int b = tid>>6, d0 = tid&63;
    float m = mu[b], r = rs[b];
    size_t ob = ((size_t)b*1024 + t)*1024;
    #pragma unroll
    for (int i=0;i<16;i++){
      int d = d0 + 64*i;
      out[ob + d] = (buf[b*1024+d]-m)*r*ln_g[d] + ln_b[d];
    }
  }
}

// ---------------- launcher ----------------
extern "C" void kernel_launch(void* const* d_in, const int* in_sizes, int n_in,
                              void* d_out, int out_size, void* d_ws, size_t ws_size,
                              hipStream_t stream){
  const float* x     = (const float*)d_in[0];
  const float* w_t1g = (const float*)d_in[1];
  const float* b_t1g = (const float*)d_in[2];
  const float* w_t1c = (const float*)d_in[3];
  const float* b_t1c = (const float*)d_in[4];
  const float* w_t1r = (const float*)d_in[5];
  const float* b_t1r = (const float*)d_in[6];
  const float* w_t2v = (const float*)d_in[7];
  const float* b_t2v = (const float*)d_in[8];
  const float* w_t2b = (const float*)d_in[9];
  const float* b_t2b = (const float*)d_in[10];
  const float* w_t2r = (const float*)d_in[11];
  const float* b_t2r = (const float*)d_in[12];
  const float* w_t3o = (const float*)d_in[13];
  const float* b_t3o = (const float*)d_in[14];
  const float* w_t3n = (const float*)d_in[15];
  const float* b_t3n = (const float*)d_in[16];
  const float* w_t3r = (const float*)d_in[17];
  const float* b_t3r = (const float*)d_in[18];
  const float* w_b32 = (const float*)d_in[19];
  const float* b_b32 = (const float*)d_in[20];
  const float* w_b21 = (const float*)d_in[21];
  const float* b_b21 = (const float*)d_in[22];
  const float* w_fuse= (const float*)d_in[23];
  const float* b_fuse= (const float*)d_in[24];
  const float* ln_g  = (const float*)d_in[25];
  const float* ln_b  = (const float*)d_in[26];
  float* out = (float*)d_out;
  (void)in_sizes; (void)n_in; (void)out_size; (void)ws_size;

  char* base = (char*)d_ws;
  size_t off = 0;
  auto alloc = [&](size_t bytes) -> void* {
    void* p = base + off;
    off += (bytes + 255) & ~(size_t)255;
    return p;
  };
  unsigned short* xtb   = (unsigned short*)alloc((size_t)B_*T_*D_*2);
  float* P              = (float*)alloc((size_t)B_*T_*512*4);
  unsigned short* traj1 = (unsigned short*)alloc((size_t)B_*T_*256*2);
  unsigned short* bm    = (unsigned short*)alloc((size_t)1024*1024*2);
  float* v      = (float*)alloc((size_t)1024*128*4);
  float* beta   = (float*)alloc(1024*4);
  float* wr1f   = (float*)alloc((size_t)256*1024*4);
  float* wr2f   = (float*)alloc((size_t)128*1024*4);
  float* wr3f   = (float*)alloc((size_t)128*1024*4);
  float* w2o    = (float*)alloc(128*64*4);
  float* w2n    = (float*)alloc(128*64*4);
  float* b2o    = (float*)alloc(64*4);
  float* b2n    = (float*)alloc(64*4);
  float* bconst = (float*)alloc(1024*4);
  float* bgc    = (float*)alloc(512*4);
  unsigned short* t2traj = (unsigned short*)alloc((size_t)1040*128*2);
  unsigned short* t3traj = (unsigned short*)alloc((size_t)144*128*2);
  float* b21seg = (float*)alloc((size_t)1040*256*4);
  float* f2seg  = (float*)alloc((size_t)1040*1024*4);
  float* f3seg  = (float*)alloc((size_t)144*1024*4);
  unsigned short* w_t1r_bf = (unsigned short*)alloc((size_t)256*1024*2);
  unsigned short* w_t2r_bf = (unsigned short*)alloc((size_t)128*1024*2);
  unsigned short* w_t3r_bf = (unsigned short*)alloc((size_t)128*1024*2);
  unsigned short* wgc1f = (unsigned short*)alloc((size_t)1024*512*2);
  unsigned short* wg2f  = (unsigned short*)alloc((size_t)256*256*2);
  unsigned short* wc2f  = (unsigned short*)alloc((size_t)256*256*2);
  unsigned short* wtvf  = (unsigned short*)alloc((size_t)1024*128*2);
  unsigned short* wb21f = (unsigned short*)alloc((size_t)128*256*2);
  unsigned short* wf1f  = (unsigned short*)alloc((size_t)1024*1024*2);
  unsigned short* wf2f  = (unsigned short*)alloc((size_t)1024*1024*2);
  unsigned short* wf3f  = (unsigned short*)alloc((size_t)1024*1024*2);
  unsigned short* w3of  = (unsigned short*)alloc((size_t)1024*64*2);
  unsigned short* w3nf  = (unsigned short*)alloc((size_t)1024*64*2);
  unsigned short* wr1ff = (unsigned short*)alloc((size_t)256*1024*2);
  unsigned short* wr2ff = (unsigned short*)alloc((size_t)128*1024*2);
  unsigned short* wr3ff = (unsigned short*)alloc((size_t)128*1024*2);

  k_f1<<<dim3(4578), dim3(256), 0, stream>>>(
      x, xtb, w_t1r, w_t1r_bf, w_t2r, w_t2r_bf, w_t3r, w_t3r_bf,
      w_t1g, w_t1c, wgc1f, wg2f, wc2f, w_t2v, wtvf, w_b21, wb21f,
      w_fuse, wf1f, wf2f, wf3f, w_t3o, w3of, w_t3n, w3nf, bm,
      b_fuse, b_t1r, b_t2r, b_t3r, bconst, b_t3o, b_t3n, b2o, b2n,
      b_t1g, b_t1c, bgc);
  k_f2<<<dim3(2468), dim3(256), 0, stream>>>(
      xtb, wgc1f, bgc, P, bm, wtvf, b_t2v, v,
      w_t1r_bf, wf1f, wr1f, w_t2r_bf, wf2f, wr2f, w_t3r_bf, wf3f, wr3f,
      w3of, w2o, w3nf, w2n, w_t2b, b_t2b, beta);
  k_f3<<<dim3(65), dim3(1024), 0, stream>>>(
      wr1f, wr1ff, wr2f, wr2ff, wr3f, wr3ff,
      v, beta, w_b32, b_b32, w2o, b2o, w2n, b2n, t2traj, t3traj);
  k_f4<<<dim3(68), dim3(256), 0, stream>>>(t2traj, wb21f, b_b21, b21seg);
  k_recur<<<dim3(192), dim3(512), 0, stream>>>(
      P, b21seg, wg2f, wc2f, traj1,
      t2traj, wr2ff, f2seg, t3traj, wr3ff, f3seg);
  k_final<<<dim3(1024), dim3(1024), 0, stream>>>(traj1, wr1ff, bconst, f2seg, f3seg, ln_g, ln_b, out);
}